// Round 4
// baseline (784.187 us; speedup 1.0000x reference)
//
#include <hip/hip_runtime.h>
#include <hip/hip_bf16.h>
#include <math.h>

#define DIM 1024
#define BATCH 16384
#define NLAYER 6

typedef __bf16 bf16_t;
typedef __attribute__((ext_vector_type(8))) __bf16 bf16x8;
typedef __attribute__((ext_vector_type(4))) float f32x4;

__device__ __forceinline__ void gload16(const void* g, void* l) {
  __builtin_amdgcn_global_load_lds(
      (const __attribute__((address_space(1))) void*)g,
      (__attribute__((address_space(3))) void*)l, 16, 0, 0);
}

__device__ __forceinline__ float fast_tanh(float x) {
  x = fminf(9.f, fmaxf(-9.f, x));
  const float e = __expf(x + x);
  return (e - 1.f) * __builtin_amdgcn_rcpf(e + 1.f);
}

__device__ __forceinline__ float bf2f(unsigned short u) {
  return __uint_as_float(((unsigned int)u) << 16);
}

// ---------------------------------------------------------------------------
// GEMM: C[m,n] = sum_k A[m,k] * W[n,k]
// MODE 0: Tb = bf16( fast_tanh(scale[m]*C + b1[n]) )
// MODE 1: hb[m,n] = cf.w*hb_old + C + b2[n] + cf.x*e[n] + cf.y*c[n] + cf.z*n[n]
//         + fused row stats (S,E,C,N) -> atomicAdd into rowstats
// MODE 2: like MODE 1 but writes fp32 outF (pre-clamp), no hb write
// K-loop: 128x128 tile, BK=64, 4 waves, 4x4 of 16x16x32 MFMA, XOR-swizzled LDS.
// Epilogue: acc staged to LDS (64 rows x 132 fp32, 2 passes), re-read so each
// thread owns 4 rows x 8 contiguous cols -> fully vectorized global I/O.
// __launch_bounds__(256,4): VGPR<=128 -> 4 blocks/CU (R2 lesson).
// ---------------------------------------------------------------------------
template <int MODE>
__global__ __launch_bounds__(256, 4) void gemm_kernel(
    const bf16_t* __restrict__ A, const bf16_t* __restrict__ W,
    const float* __restrict__ bias, bf16_t* __restrict__ outB,
    float* __restrict__ outF, const f32x4* __restrict__ coef,
    const float* __restrict__ dirs, const float* __restrict__ scaleArr,
    const bf16_t* __restrict__ hbIn, float* __restrict__ rowstats) {
  __shared__ __align__(16) char smem[33792];
  bf16_t* sA = (bf16_t*)smem;             // 16 KB (K-loop)
  bf16_t* sB = (bf16_t*)(smem + 16384);   // 16 KB (K-loop)
  float* sC = (float*)smem;               // 33 KB (epilogue, aliases sA/sB)

  const int tid = threadIdx.x;
  const int w = tid >> 6;
  const int lane = tid & 63;
  const int bm = blockIdx.x * 128;
  const int bn = blockIdx.y * 128;
  const int wm = (w & 1) * 64;
  const int wn = (w >> 1) * 64;
  const int lm = lane & 15;
  const int lc = lane >> 4;  // 0..3

  f32x4 acc[4][4] = {};

  // staging: thread -> (row srow = tid>>3, phys chunk p = tid&7)
  const int srow = tid >> 3;
  const int swz = ((tid & 7) ^ (srow & 7)) * 8;
  const bf16_t* gA = A + (size_t)(bm + srow) * DIM + swz;
  const bf16_t* gW = W + (size_t)(bn + srow) * DIM + swz;
  char* lA = (char*)sA + w * 1024;
  char* lB = (char*)sB + w * 1024;

  for (int kt = 0; kt < DIM; kt += 64) {
#pragma unroll
    for (int q = 0; q < 4; ++q) {
      gload16(gA + kt + (size_t)q * 32 * DIM, lA + q * 4096);
      gload16(gW + kt + (size_t)q * 32 * DIM, lB + q * 4096);
    }
    __syncthreads();
#pragma unroll
    for (int kh = 0; kh < 2; ++kh) {
      bf16x8 aF[4], bF[4];
      const int lgc = kh * 4 + lc;
#pragma unroll
      for (int i = 0; i < 4; ++i) {
        const int rowA = wm + i * 16 + lm;
        aF[i] = *(const bf16x8*)((char*)sA + rowA * 128 +
                                 ((lgc ^ (lm & 7)) << 4));
      }
#pragma unroll
      for (int j = 0; j < 4; ++j) {
        const int rowB = wn + j * 16 + lm;
        bF[j] = *(const bf16x8*)((char*)sB + rowB * 128 +
                                 ((lgc ^ (lm & 7)) << 4));
      }
#pragma unroll
      for (int i = 0; i < 4; ++i)
#pragma unroll
        for (int j = 0; j < 4; ++j)
          acc[i][j] = __builtin_amdgcn_mfma_f32_16x16x32_bf16(
              aF[i], bF[j], acc[i][j], 0, 0, 0);
    }
    __syncthreads();
  }
  // after final sync, LDS free for epilogue staging

  const int rg = tid >> 4;        // 0..15 -> rows rg*4..rg*4+3 (within pass)
  const int cg = tid & 15;        // 0..15 -> cols cg*8..cg*8+7
  const int colBase = cg * 8;
  const int gcol = bn + colBase;

  // column-constant data (16B loads, L2/L3-hot)
  float4 e0, e1, c0, c1, n0, n1, b0, b1v;
  if constexpr (MODE != 0) {
    e0 = *(const float4*)&dirs[gcol];           e1 = *(const float4*)&dirs[gcol + 4];
    c0 = *(const float4*)&dirs[DIM + gcol];     c1 = *(const float4*)&dirs[DIM + gcol + 4];
    n0 = *(const float4*)&dirs[2 * DIM + gcol]; n1 = *(const float4*)&dirs[2 * DIM + gcol + 4];
  }
  b0 = *(const float4*)&bias[gcol];
  b1v = *(const float4*)&bias[gcol + 4];

#pragma unroll
  for (int p = 0; p < 2; ++p) {
    if (p) __syncthreads();  // pass-0 reads complete before overwrite
    if (wm == p * 64) {
      // stage this wave's acc: row (i*16+lc*4+r), col (wn+j*16+lm)
#pragma unroll
      for (int i = 0; i < 4; ++i)
#pragma unroll
        for (int j = 0; j < 4; ++j)
#pragma unroll
          for (int r = 0; r < 4; ++r)
            sC[(i * 16 + lc * 4 + r) * 132 + wn + j * 16 + lm] = acc[i][j][r];
    }
    __syncthreads();

    const int lr0 = rg * 4;
    const int grow0 = bm + p * 64 + lr0;
#pragma unroll
    for (int r = 0; r < 4; ++r) {
      const float4 v0 = *(const float4*)&sC[(lr0 + r) * 132 + colBase];
      const float4 v1 = *(const float4*)&sC[(lr0 + r) * 132 + colBase + 4];
      const int grow = grow0 + r;
      if constexpr (MODE == 0) {
        const float s = scaleArr[grow];
        bf16x8 o;
        o[0] = (bf16_t)fast_tanh(s * v0.x + b0.x);
        o[1] = (bf16_t)fast_tanh(s * v0.y + b0.y);
        o[2] = (bf16_t)fast_tanh(s * v0.z + b0.z);
        o[3] = (bf16_t)fast_tanh(s * v0.w + b0.w);
        o[4] = (bf16_t)fast_tanh(s * v1.x + b1v.x);
        o[5] = (bf16_t)fast_tanh(s * v1.y + b1v.y);
        o[6] = (bf16_t)fast_tanh(s * v1.z + b1v.z);
        o[7] = (bf16_t)fast_tanh(s * v1.w + b1v.w);
        *(bf16x8*)&outB[(size_t)grow * DIM + gcol] = o;
      } else {
        const f32x4 cf = coef[grow];
        const bf16x8 hp = *(const bf16x8*)&hbIn[(size_t)grow * DIM + gcol];
        float vv[8];
        vv[0] = v0.x + b0.x + cf.x * e0.x + cf.y * c0.x + cf.z * n0.x + cf.w * (float)hp[0];
        vv[1] = v0.y + b0.y + cf.x * e0.y + cf.y * c0.y + cf.z * n0.y + cf.w * (float)hp[1];
        vv[2] = v0.z + b0.z + cf.x * e0.z + cf.y * c0.z + cf.z * n0.z + cf.w * (float)hp[2];
        vv[3] = v0.w + b0.w + cf.x * e0.w + cf.y * c0.w + cf.z * n0.w + cf.w * (float)hp[3];
        vv[4] = v1.x + b1v.x + cf.x * e1.x + cf.y * c1.x + cf.z * n1.x + cf.w * (float)hp[4];
        vv[5] = v1.y + b1v.y + cf.x * e1.y + cf.y * c1.y + cf.z * n1.y + cf.w * (float)hp[5];
        vv[6] = v1.z + b1v.z + cf.x * e1.z + cf.y * c1.z + cf.z * n1.z + cf.w * (float)hp[6];
        vv[7] = v1.w + b1v.w + cf.x * e1.w + cf.y * c1.w + cf.z * n1.w + cf.w * (float)hp[7];
        if constexpr (MODE == 1) {
          bf16x8 o;
#pragma unroll
          for (int q = 0; q < 8; ++q) o[q] = (bf16_t)vv[q];
          *(bf16x8*)&outB[(size_t)grow * DIM + gcol] = o;
        } else {
          float4 o0, o1;
          o0.x = vv[0]; o0.y = vv[1]; o0.z = vv[2]; o0.w = vv[3];
          o1.x = vv[4]; o1.y = vv[5]; o1.z = vv[6]; o1.w = vv[7];
          *(float4*)&outF[(size_t)grow * DIM + gcol] = o0;
          *(float4*)&outF[(size_t)grow * DIM + gcol + 4] = o1;
        }
        // fused row stats: S=sum v^2, E=sum v*e, C=sum v*c, N=sum v*n
        float ss = 0, de = 0, dc = 0, dn = 0;
        const float ea[8] = {e0.x, e0.y, e0.z, e0.w, e1.x, e1.y, e1.z, e1.w};
        const float ca[8] = {c0.x, c0.y, c0.z, c0.w, c1.x, c1.y, c1.z, c1.w};
        const float na[8] = {n0.x, n0.y, n0.z, n0.w, n1.x, n1.y, n1.z, n1.w};
#pragma unroll
        for (int q = 0; q < 8; ++q) {
          ss += vv[q] * vv[q];
          de += vv[q] * ea[q];
          dc += vv[q] * ca[q];
          dn += vv[q] * na[q];
        }
#pragma unroll
        for (int off = 8; off; off >>= 1) {
          ss += __shfl_down(ss, off, 16);
          de += __shfl_down(de, off, 16);
          dc += __shfl_down(dc, off, 16);
          dn += __shfl_down(dn, off, 16);
        }
        if (cg == 0) {
          atomicAdd(&rowstats[grow * 4 + 0], ss);
          atomicAdd(&rowstats[grow * 4 + 1], de);
          atomicAdd(&rowstats[grow * 4 + 2], dc);
          atomicAdd(&rowstats[grow * 4 + 3], dn);
        }
      }
    }
  }
}

// rowstats {S,E,C,N} -> scaleArr + coef (clamp always on here; layers >=1)
__global__ __launch_bounds__(256) void finalize_stats(
    const f32x4* __restrict__ rowstats, float* __restrict__ scaleArr,
    f32x4* __restrict__ coef) {
  const int row = blockIdx.x * 256 + threadIdx.x;
  const f32x4 rs = rowstats[row];
  const float norm = sqrtf(rs.x);
  float scale = 1.f;
  if (norm > 10.f) scale = 10.f / (norm + 1e-8f);
  const float invn = 1.f / fmaxf(norm, 1e-12f);
  const float ae = rs.y * invn;
  const float ac = rs.z * invn;
  const float an = rs.w * invn;
  const float nc = norm * scale;
  const float re = sqrtf(fmaxf(nc * nc - 2.f * nc * ae + 1.f, 0.f));
  const float rc = sqrtf(fmaxf(nc * nc - 2.f * nc * ac + 1.f, 0.f));
  const float rn = sqrtf(fmaxf(nc * nc - 2.f * nc * an + 1.f, 0.f));
  const float boundary = fminf(fmaxf(1.f - fabsf(ae - ac), 0.f), 1.f);
  f32x4 cf;
  cf.x = 0.1f * (1.f - ae) / fmaxf(re, 1e-12f);
  cf.y = 0.1f * (1.f - ac) / fmaxf(rc, 1e-12f);
  cf.z = (0.05f * (1.f - an) + 0.05f * boundary) / fmaxf(rn, 1e-12f);
  cf.w = scale * (1.f - cf.x - cf.y - cf.z);
  coef[row] = cf;
  scaleArr[row] = scale;
}

// layer-0 stats from fp32 h0 (also casts h0 -> hb); no clamp
__global__ __launch_bounds__(256) void stats0_kernel(
    const float* __restrict__ src, bf16_t* __restrict__ dstb,
    float* __restrict__ scaleArr, f32x4* __restrict__ coef,
    const float* __restrict__ dirs) {
  const int row = blockIdx.x;
  const int t = threadIdx.x;
  const float4 v = ((const float4*)src)[(size_t)row * 256 + t];
  const float4 e = ((const float4*)dirs)[t];
  const float4 c = ((const float4*)dirs)[t + 256];
  const float4 n = ((const float4*)dirs)[t + 512];
  float ss = v.x * v.x + v.y * v.y + v.z * v.z + v.w * v.w;
  float de = v.x * e.x + v.y * e.y + v.z * e.z + v.w * e.w;
  float dc = v.x * c.x + v.y * c.y + v.z * c.z + v.w * c.w;
  float dn = v.x * n.x + v.y * n.y + v.z * n.z + v.w * n.w;
#pragma unroll
  for (int off = 32; off; off >>= 1) {
    ss += __shfl_down(ss, off);
    de += __shfl_down(de, off);
    dc += __shfl_down(dc, off);
    dn += __shfl_down(dn, off);
  }
  __shared__ float red[4][4];
  const int w = t >> 6;
  if ((t & 63) == 0) {
    red[w][0] = ss; red[w][1] = de; red[w][2] = dc; red[w][3] = dn;
  }
  __syncthreads();
  union { bf16_t b[4]; uint2 u; } pk;
  pk.b[0] = (bf16_t)v.x; pk.b[1] = (bf16_t)v.y;
  pk.b[2] = (bf16_t)v.z; pk.b[3] = (bf16_t)v.w;
  ((uint2*)dstb)[(size_t)row * 256 + t] = pk.u;
  if (t == 0) {
    float S = 0, E = 0, C = 0, N = 0;
#pragma unroll
    for (int i = 0; i < 4; ++i) {
      S += red[i][0]; E += red[i][1]; C += red[i][2]; N += red[i][3];
    }
    const float norm = sqrtf(S);
    const float scale = 1.f;  // no clamp on h0
    const float invn = 1.f / fmaxf(norm, 1e-12f);
    const float ae = E * invn, ac = C * invn, an = N * invn;
    const float nc = norm;
    const float re = sqrtf(fmaxf(nc * nc - 2.f * nc * ae + 1.f, 0.f));
    const float rc = sqrtf(fmaxf(nc * nc - 2.f * nc * ac + 1.f, 0.f));
    const float rn = sqrtf(fmaxf(nc * nc - 2.f * nc * an + 1.f, 0.f));
    const float boundary = fminf(fmaxf(1.f - fabsf(ae - ac), 0.f), 1.f);
    f32x4 cf;
    cf.x = 0.1f * (1.f - ae) / fmaxf(re, 1e-12f);
    cf.y = 0.1f * (1.f - ac) / fmaxf(rc, 1e-12f);
    cf.z = (0.05f * (1.f - an) + 0.05f * boundary) / fmaxf(rn, 1e-12f);
    cf.w = scale * (1.f - cf.x - cf.y - cf.z);
    coef[row] = cf;
    scaleArr[row] = scale;
  }
}

__global__ __launch_bounds__(256) void finalize_kernel(
    float* __restrict__ outF, const float* __restrict__ scaleArr) {
  const int row = blockIdx.x;
  const int t = threadIdx.x;
  const float s = scaleArr[row];
  float4 v = ((float4*)outF)[(size_t)row * 256 + t];
  v.x *= s; v.y *= s; v.z *= s; v.w *= s;
  ((float4*)outF)[(size_t)row * 256 + t] = v;
}

__global__ __launch_bounds__(256) void prep_dirs(
    const float* __restrict__ ae, const float* __restrict__ ac,
    const float* __restrict__ an, float* __restrict__ dirs) {
  const int t = threadIdx.x;
  const float4 a = ((const float4*)ae)[t];
  const float4 b = ((const float4*)ac)[t];
  const float4 c = ((const float4*)an)[t];
  float sa = a.x * a.x + a.y * a.y + a.z * a.z + a.w * a.w;
  float sb = b.x * b.x + b.y * b.y + b.z * b.z + b.w * b.w;
  float sc = c.x * c.x + c.y * c.y + c.z * c.z + c.w * c.w;
#pragma unroll
  for (int off = 32; off; off >>= 1) {
    sa += __shfl_down(sa, off);
    sb += __shfl_down(sb, off);
    sc += __shfl_down(sc, off);
  }
  __shared__ float red[4][3];
  __shared__ float fin[3];
  const int w = t >> 6;
  if ((t & 63) == 0) { red[w][0] = sa; red[w][1] = sb; red[w][2] = sc; }
  __syncthreads();
  if (t == 0) {
    float x = 0, y = 0, z = 0;
#pragma unroll
    for (int i = 0; i < 4; ++i) { x += red[i][0]; y += red[i][1]; z += red[i][2]; }
    fin[0] = x; fin[1] = y; fin[2] = z;
  }
  __syncthreads();
  const float ia = 1.f / fmaxf(sqrtf(fin[0]), 1e-12f);
  const float ib = 1.f / fmaxf(sqrtf(fin[1]), 1e-12f);
  const float ic = 1.f / fmaxf(sqrtf(fin[2]), 1e-12f);
  float4 oa, ob, oc;
  oa.x = a.x * ia; oa.y = a.y * ia; oa.z = a.z * ia; oa.w = a.w * ia;
  ob.x = b.x * ib; ob.y = b.y * ib; ob.z = b.z * ib; ob.w = b.w * ib;
  oc.x = c.x * ic; oc.y = c.y * ic; oc.z = c.z * ic; oc.w = c.w * ic;
  ((float4*)dirs)[t] = oa;
  ((float4*)dirs)[t + 256] = ob;
  ((float4*)dirs)[t + 512] = oc;
}

__global__ __launch_bounds__(256) void cast_w_kernel(
    const float* __restrict__ W, bf16_t* __restrict__ Wb) {
  const int i = blockIdx.x * 256 + threadIdx.x;
  const float4 v = ((const float4*)W)[i];
  union { bf16_t b[4]; uint2 u; } pk;
  pk.b[0] = (bf16_t)v.x; pk.b[1] = (bf16_t)v.y;
  pk.b[2] = (bf16_t)v.z; pk.b[3] = (bf16_t)v.w;
  ((uint2*)Wb)[i] = pk.u;
}

extern "C" void kernel_launch(void* const* d_in, const int* in_sizes, int n_in,
                              void* d_out, int out_size, void* d_ws,
                              size_t ws_size, hipStream_t stream) {
  const float* h0 = (const float*)d_in[0];
  const float* W1 = (const float*)d_in[1];
  const float* b1 = (const float*)d_in[2];
  const float* W2 = (const float*)d_in[3];
  const float* b2 = (const float*)d_in[4];
  const float* ae = (const float*)d_in[5];
  const float* ac = (const float*)d_in[6];
  const float* an = (const float*)d_in[7];
  float* outF = (float*)d_out;

  char* ws = (char*)d_ws;
  bf16_t* hb = (bf16_t*)ws;  ws += (size_t)BATCH * DIM * 2;   // 32 MB
  bf16_t* Tb = (bf16_t*)ws;  ws += (size_t)BATCH * DIM * 2;   // 32 MB
  bf16_t* W1b = (bf16_t*)ws; ws += (size_t)DIM * DIM * 2;     // 2 MB
  bf16_t* W2b = (bf16_t*)ws; ws += (size_t)DIM * DIM * 2;     // 2 MB
  float* dirs = (float*)ws;  ws += 3 * DIM * 4;
  f32x4* coef = (f32x4*)ws;  ws += (size_t)BATCH * 16;
  float* scaleArr = (float*)ws; ws += (size_t)BATCH * 4;
  float* rowstats = (float*)ws; ws += (size_t)NLAYER * BATCH * 16;  // 1.5 MB

  hipMemsetAsync(rowstats, 0, (size_t)NLAYER * BATCH * 16, stream);
  prep_dirs<<<1, 256, 0, stream>>>(ae, ac, an, dirs);
  cast_w_kernel<<<DIM * DIM / 1024, 256, 0, stream>>>(W1, W1b);
  cast_w_kernel<<<DIM * DIM / 1024, 256, 0, stream>>>(W2, W2b);
  stats0_kernel<<<BATCH, 256, 0, stream>>>(h0, hb, scaleArr, coef, dirs);

  dim3 grid(BATCH / 128, DIM / 128);
  for (int l = 0; l < NLAYER; ++l) {
    gemm_kernel<0><<<grid, 256, 0, stream>>>(hb, W1b, b1, Tb, nullptr, nullptr,
                                             nullptr, scaleArr, nullptr,
                                             nullptr);
    float* rs = rowstats + (size_t)l * BATCH * 4;
    if (l < NLAYER - 1) {
      gemm_kernel<1><<<grid, 256, 0, stream>>>(Tb, W2b, b2, hb, nullptr, coef,
                                               dirs, nullptr, hb, rs);
    } else {
      gemm_kernel<2><<<grid, 256, 0, stream>>>(Tb, W2b, b2, nullptr, outF, coef,
                                               dirs, nullptr, hb, rs);
    }
    finalize_stats<<<BATCH / 256, 256, 0, stream>>>((const f32x4*)rs, scaleArr,
                                                    coef);
    if (l == NLAYER - 1)
      finalize_kernel<<<BATCH, 256, 0, stream>>>(outF, scaleArr);
  }
}